// Round 2
// baseline (331.147 us; speedup 1.0000x reference)
//
#include <hip/hip_runtime.h>
#include <math.h>

// ProtoPNet forward on MI355X.
// outputs concat: [x (6422528) | min_dists (128000) | dists (25088000) | activations (128000) | logits (12800)]

#define EPSV 1e-4f

constexpr int NB  = 64;
constexpr int NC  = 512;
constexpr int NHW = 196;
constexpr int NP  = 2000;
constexpr int NCL = 200;
constexpr int MM   = NB * NHW;        // 12544
constexpr int XTOT = NB * NC * NHW;   // 6422528

constexpr long long OFF_MIN = XTOT;
constexpr long long OFF_D   = OFF_MIN + (long long)NB * NP;
constexpr long long OFF_ACT = OFF_D + (long long)NB * NP * NHW;
constexpr long long OFF_LOG = OFF_ACT + (long long)NB * NP;

typedef __attribute__((ext_vector_type(8))) short short8;
typedef __attribute__((ext_vector_type(4))) float f32x4;

// split f32 -> bf16 hi (RNE) + bf16 lo (RNE of exact residual)
__device__ __forceinline__ void bsplit(float f, unsigned& h, unsigned& l) {
    unsigned u = __float_as_uint(f);
    h = (u + 0x7FFFu + ((u >> 16) & 1u)) >> 16;
    float fl = f - __uint_as_float(h << 16);
    unsigned u2 = __float_as_uint(fl);
    l = (u2 + 0x7FFFu + ((u2 >> 16) & 1u)) >> 16;
}

// ---------- prep: transpose+split x -> xh/xl [m][c] bf16 ----------
__global__ __launch_bounds__(256) void splitx_kernel(const float* __restrict__ x,
                                                     unsigned short* __restrict__ xh,
                                                     unsigned short* __restrict__ xl) {
    __shared__ float tl[64 * 197];
    const int b = blockIdx.x >> 3, cc = blockIdx.x & 7;
    const int c0 = cc * 64;
    const float* src = x + ((size_t)b * NC + c0) * NHW;
    for (int idx = threadIdx.x; idx < 64 * 196; idx += 256) {   // 49 iters exact
        int cl = idx / 196, hw = idx - cl * 196;
        tl[cl * 197 + hw] = src[cl * 196 + hw];
    }
    __syncthreads();
    for (int idx = threadIdx.x; idx < 64 * 196; idx += 256) {
        int hw = idx >> 6, cl = idx & 63;
        float v = tl[cl * 197 + hw];
        unsigned h, l; bsplit(v, h, l);
        size_t o = ((size_t)(b * 196 + hw)) * NC + c0 + cl;
        xh[o] = (unsigned short)h;
        xl[o] = (unsigned short)l;
    }
}

// ---------- prep: p2[p] = sum_c proto^2 ----------
__global__ void p2_kernel(const float* __restrict__ proto, float* __restrict__ p2) {
    int p = blockIdx.x * 4 + (threadIdx.x >> 6);
    int l = threadIdx.x & 63;
    const float* row = proto + p * NC;
    float s = 0.f;
    #pragma unroll
    for (int k = 0; k < NC / 64; ++k) { float v = row[l + 64 * k]; s += v * v; }
    for (int off = 32; off; off >>= 1) s += __shfl_down(s, off, 64);
    if (l == 0) p2[p] = s;
}

// ---------- prep: x2 partials (4 chunks of 128 c) ----------
__global__ void x2_kernel(const float* __restrict__ x, float* __restrict__ x2p) {
    int b = blockIdx.x >> 2, q = blockIdx.x & 3;
    int t = threadIdx.x;
    if (t >= NHW) return;
    const float* base = x + (size_t)b * (NC * NHW) + t;
    float s = 0.f;
    #pragma unroll 4
    for (int c = q * 128; c < q * 128 + 128; ++c) { float v = base[c * NHW]; s += v * v; }
    x2p[q * MM + b * NHW + t] = s;
}

// ---------- main: split-bf16 MFMA GEMM + dists epilogue ----------
// A-operand = proto rows (p), B-operand = pixel columns (m). 128x128 tile, BK=32.
__global__ __launch_bounds__(256) void gemm_dists(
    const unsigned short* __restrict__ xh, const unsigned short* __restrict__ xl,
    const float* __restrict__ proto, const float* __restrict__ p2,
    const float* __restrict__ x2p, float* __restrict__ dists)
{
    __shared__ unsigned short Ah[128][40];  // pixel tiles (B-operand source)
    __shared__ unsigned short Al[128][40];
    __shared__ unsigned short Bh[128][40];  // proto tiles (A-operand source)
    __shared__ unsigned short Bl[128][40];

    const int mt = blockIdx.x;   // 0..97 pixel tiles
    const int nt = blockIdx.y;   // 0..15 proto tiles (last ragged)
    const int t = threadIdx.x;
    const int lane = t & 63, lm = lane & 15, kg = lane >> 4;
    const int w = t >> 6, wp = w >> 1, wx = w & 1;

    // staging: thread -> (row sm, 16-elem half sh)
    const int sm = t >> 1, sh = t & 1;
    const size_t arow = (size_t)(mt * 128 + sm) * NC + sh * 16;
    const int gp = nt * 128 + sm;
    const bool pv = gp < NP;
    const float* bp = proto + (size_t)(pv ? gp : 0) * NC + sh * 16;

    f32x4 acc[4][4];
    #pragma unroll
    for (int i = 0; i < 4; ++i)
        #pragma unroll
        for (int j = 0; j < 4; ++j) acc[i][j] = 0.f;

    for (int c0 = 0; c0 < NC; c0 += 32) {
        // A (pixels): pure bf16 copy from pre-split xh/xl
        const uint4* pah = (const uint4*)(xh + arow + c0);
        const uint4* pal = (const uint4*)(xl + arow + c0);
        uint4 vh0 = pah[0], vh1 = pah[1], vl0 = pal[0], vl1 = pal[1];
        // B (protos): f32 read + in-register split
        float4 f0, f1, f2, f3;
        if (pv) {
            const float4* pb = (const float4*)(bp + c0);
            f0 = pb[0]; f1 = pb[1]; f2 = pb[2]; f3 = pb[3];
        } else {
            f0 = f1 = f2 = f3 = make_float4(0.f, 0.f, 0.f, 0.f);
        }
        *(uint4*)&Ah[sm][sh * 16]     = vh0;
        *(uint4*)&Ah[sm][sh * 16 + 8] = vh1;
        *(uint4*)&Al[sm][sh * 16]     = vl0;
        *(uint4*)&Al[sm][sh * 16 + 8] = vl1;
        {
            unsigned a, b_, c, d;
            bsplit(f0.x, a, c); bsplit(f0.y, b_, d);
            unsigned wh0 = a | (b_ << 16), wl0 = c | (d << 16);
            bsplit(f0.z, a, c); bsplit(f0.w, b_, d);
            *(uint2*)&Bh[sm][sh * 16 + 0] = make_uint2(wh0, a | (b_ << 16));
            *(uint2*)&Bl[sm][sh * 16 + 0] = make_uint2(wl0, c | (d << 16));
            bsplit(f1.x, a, c); bsplit(f1.y, b_, d);
            wh0 = a | (b_ << 16); wl0 = c | (d << 16);
            bsplit(f1.z, a, c); bsplit(f1.w, b_, d);
            *(uint2*)&Bh[sm][sh * 16 + 4] = make_uint2(wh0, a | (b_ << 16));
            *(uint2*)&Bl[sm][sh * 16 + 4] = make_uint2(wl0, c | (d << 16));
            bsplit(f2.x, a, c); bsplit(f2.y, b_, d);
            wh0 = a | (b_ << 16); wl0 = c | (d << 16);
            bsplit(f2.z, a, c); bsplit(f2.w, b_, d);
            *(uint2*)&Bh[sm][sh * 16 + 8] = make_uint2(wh0, a | (b_ << 16));
            *(uint2*)&Bl[sm][sh * 16 + 8] = make_uint2(wl0, c | (d << 16));
            bsplit(f3.x, a, c); bsplit(f3.y, b_, d);
            wh0 = a | (b_ << 16); wl0 = c | (d << 16);
            bsplit(f3.z, a, c); bsplit(f3.w, b_, d);
            *(uint2*)&Bh[sm][sh * 16 + 12] = make_uint2(wh0, a | (b_ << 16));
            *(uint2*)&Bl[sm][sh * 16 + 12] = make_uint2(wl0, c | (d << 16));
        }
        __syncthreads();

        short8 Ph[4], Plo[4], Xh[4], Xlo[4];
        #pragma unroll
        for (int i = 0; i < 4; ++i) {
            Ph[i]  = *(const short8*)&Bh[wp * 64 + i * 16 + lm][kg * 8];
            Plo[i] = *(const short8*)&Bl[wp * 64 + i * 16 + lm][kg * 8];
            Xh[i]  = *(const short8*)&Ah[wx * 64 + i * 16 + lm][kg * 8];
            Xlo[i] = *(const short8*)&Al[wx * 64 + i * 16 + lm][kg * 8];
        }
        #pragma unroll
        for (int i = 0; i < 4; ++i)
            #pragma unroll
            for (int j = 0; j < 4; ++j) {
                acc[i][j] = __builtin_amdgcn_mfma_f32_16x16x32_bf16(Ph[i],  Xh[j],  acc[i][j], 0, 0, 0);
                acc[i][j] = __builtin_amdgcn_mfma_f32_16x16x32_bf16(Plo[i], Xh[j],  acc[i][j], 0, 0, 0);
                acc[i][j] = __builtin_amdgcn_mfma_f32_16x16x32_bf16(Ph[i],  Xlo[j], acc[i][j], 0, 0, 0);
            }
        __syncthreads();
    }

    // epilogue: dists = relu(x2 - 2*xp + p2)
    float x2v[4]; size_t dbase[4];
    #pragma unroll
    for (int j = 0; j < 4; ++j) {
        int m = mt * 128 + wx * 64 + j * 16 + lm;
        x2v[j] = x2p[m] + x2p[MM + m] + x2p[2 * MM + m] + x2p[3 * MM + m];
        int b = m / NHW, hw = m - b * NHW;
        dbase[j] = (size_t)b * NP * NHW + hw;
    }
    #pragma unroll
    for (int i = 0; i < 4; ++i)
        #pragma unroll
        for (int r = 0; r < 4; ++r) {
            int p = nt * 128 + wp * 64 + i * 16 + kg * 4 + r;
            if (p < NP) {
                float p2v = p2[p];
                #pragma unroll
                for (int j = 0; j < 4; ++j) {
                    float v = fmaxf(x2v[j] - 2.f * acc[i][j][r] + p2v, 0.f);
                    dists[dbase[j] + (size_t)p * NHW] = v;
                }
            }
        }
}

// ---------- min over hw + activations ----------
__global__ void minact_kernel(const float* __restrict__ dists,
                              float* __restrict__ mind, float* __restrict__ act) {
    int r = blockIdx.x * 4 + (threadIdx.x >> 6);
    int l = threadIdx.x & 63;
    const float* row = dists + (size_t)r * NHW;
    float v = 3.4e38f;
    for (int k = l; k < NHW; k += 64) v = fminf(v, row[k]);
    for (int off = 32; off; off >>= 1) v = fminf(v, __shfl_down(v, off, 64));
    if (l == 0) {
        mind[r] = v;
        act[r] = logf((v + 1.f) / (v + EPSV));
    }
}

// ---------- logits = act @ fc^T ----------
__global__ void logits_kernel(const float* __restrict__ act,
                              const float* __restrict__ fc, float* __restrict__ out) {
    int r = blockIdx.x * 4 + (threadIdx.x >> 6);
    int l = threadIdx.x & 63;
    int b = r / NCL, n = r - b * NCL;
    const float* arow = act + b * NP;
    const float* frow = fc + n * NP;
    float s = 0.f;
    for (int k = l; k < NP; k += 64) s += arow[k] * frow[k];
    for (int off = 32; off; off >>= 1) s += __shfl_down(s, off, 64);
    if (l == 0) out[r] = s;
}

// ---------- x passthrough (runs LAST: overwrites xh/xl scratch) ----------
__global__ void copy_kernel(const float4* __restrict__ in, float4* __restrict__ out, int n4) {
    for (int i = blockIdx.x * blockDim.x + threadIdx.x; i < n4; i += gridDim.x * blockDim.x)
        out[i] = in[i];
}

extern "C" void kernel_launch(void* const* d_in, const int* in_sizes, int n_in,
                              void* d_out, int out_size, void* d_ws, size_t ws_size,
                              hipStream_t stream) {
    const float* x     = (const float*)d_in[0];
    const float* proto = (const float*)d_in[1];
    const float* fc    = (const float*)d_in[2];
    float* out = (float*)d_out;

    // scratch: xh/xl fill the x-output region exactly (overwritten by copy_kernel last);
    // p2/x2p live in the min_dists region (overwritten by minact after gemm reads them).
    unsigned short* xh = (unsigned short*)out;      // XTOT bf16
    unsigned short* xl = xh + XTOT;                 // XTOT bf16
    float* p2  = out + OFF_MIN;                     // 2000 (pad 2048)
    float* x2p = out + OFF_MIN + 2048;              // 4*12544

    float* mind  = out + OFF_MIN;
    float* dists = out + OFF_D;
    float* act   = out + OFF_ACT;
    float* logit = out + OFF_LOG;

    splitx_kernel<<<512, 256, 0, stream>>>(x, xh, xl);
    p2_kernel<<<500, 256, 0, stream>>>(proto, p2);
    x2_kernel<<<256, 256, 0, stream>>>(x, x2p);

    gemm_dists<<<dim3(98, 16), 256, 0, stream>>>(xh, xl, proto, p2, x2p, dists);

    minact_kernel<<<32000, 256, 0, stream>>>(dists, mind, act);
    logits_kernel<<<3200, 256, 0, stream>>>(act, fc, logit);

    copy_kernel<<<2048, 256, 0, stream>>>((const float4*)x, (float4*)out, XTOT / 4);
}

// Round 3
// 305.168 us; speedup vs baseline: 1.0851x; 1.0851x over previous
//
#include <hip/hip_runtime.h>
#include <math.h>

// ProtoPNet forward on MI355X (gfx950).
// out concat: [x (6422528) | min_dists (128000) | dists (25088000) | activations (128000) | logits (12800)]

#define EPSV 1e-4f
typedef unsigned short ushort_t;

constexpr int NB  = 64;
constexpr int NC  = 512;
constexpr int NHW = 196;
constexpr int NP  = 2000;
constexpr int NPAD = 2048;   // proto rows padded (zero) -> no ragged tiles
constexpr int NCL = 200;
constexpr int MM   = NB * NHW;        // 12544 = 98*128
constexpr int XTOT = NB * NC * NHW;   // 6422528

constexpr long long OFF_MIN = XTOT;
constexpr long long OFF_D   = OFF_MIN + (long long)NB * NP;
constexpr long long OFF_ACT = OFF_D + (long long)NB * NP * NHW;
constexpr long long OFF_LOG = OFF_ACT + (long long)NB * NP;

typedef __attribute__((ext_vector_type(8))) short short8;
typedef __attribute__((ext_vector_type(4))) float f32x4;

// f32 -> bf16 hi (RNE) + bf16 lo (RNE of residual)
__device__ __forceinline__ void bsplit(float f, unsigned& h, unsigned& l) {
    unsigned u = __float_as_uint(f);
    h = (u + 0x7FFFu + ((u >> 16) & 1u)) >> 16;
    float fl = f - __uint_as_float(h << 16);
    unsigned u2 = __float_as_uint(fl);
    l = (u2 + 0x7FFFu + ((u2 >> 16) & 1u)) >> 16;
}

__device__ __forceinline__ void gl_lds16(const void* g, void* l) {
    __builtin_amdgcn_global_load_lds(
        (const __attribute__((address_space(1))) unsigned int*)g,
        (__attribute__((address_space(3))) unsigned int*)l, 16, 0, 0);
}

// ---------- init: mind=+MAX (for uint atomicMin on nonneg floats), x2=0 ----------
__global__ void fill_kernel(float* __restrict__ mind, float* __restrict__ x2) {
    int i = blockIdx.x * 256 + threadIdx.x;
    if (i < NB * NP) mind[i] = 3.402823466e38f;
    if (i < MM)      x2[i] = 0.f;
}

// ---------- x -> xh/xl [m][c] bf16 (transpose+split), and x2[m] += partial ----------
__global__ __launch_bounds__(256) void splitx_kernel(const float* __restrict__ x,
                                                     ushort_t* __restrict__ xh,
                                                     ushort_t* __restrict__ xl,
                                                     float* __restrict__ x2) {
    __shared__ float tl[64 * 197];
    const int b = blockIdx.x >> 3, cc = blockIdx.x & 7;
    const int c0 = cc * 64;
    const float* src = x + ((size_t)b * NC + c0) * NHW;
    for (int idx = threadIdx.x; idx < 64 * 196; idx += 256) {
        int cl = idx / 196, hw = idx - cl * 196;
        tl[cl * 197 + hw] = src[idx];
    }
    __syncthreads();
    for (int idx = threadIdx.x; idx < 64 * 196; idx += 256) {
        int hw = idx >> 6, cl = idx & 63;
        float v = tl[cl * 197 + hw];
        unsigned h, l; bsplit(v, h, l);
        size_t o = ((size_t)(b * 196 + hw)) * NC + c0 + cl;
        xh[o] = (ushort_t)h;
        xl[o] = (ushort_t)l;
    }
    if (threadIdx.x < 196) {
        float s = 0.f;
        #pragma unroll 8
        for (int cl = 0; cl < 64; ++cl) { float v = tl[cl * 197 + threadIdx.x]; s += v * v; }
        atomicAdd(&x2[b * 196 + threadIdx.x], s);
    }
}

// ---------- proto -> ph/pl [2048][512] bf16 (zero-padded) + p2 ----------
__global__ void splitp_kernel(const float* __restrict__ proto,
                              ushort_t* __restrict__ ph, ushort_t* __restrict__ pl,
                              float* __restrict__ p2) {
    int p = blockIdx.x * 4 + (threadIdx.x >> 6);   // < 2048
    int l = threadIdx.x & 63;
    unsigned hs[8], ls[8];
    float s = 0.f;
    if (p < NP) {
        const float4* pr = (const float4*)(proto + (size_t)p * NC + l * 8);
        float4 a = pr[0], bb = pr[1];
        float vv[8] = {a.x, a.y, a.z, a.w, bb.x, bb.y, bb.z, bb.w};
        #pragma unroll
        for (int k = 0; k < 8; ++k) { bsplit(vv[k], hs[k], ls[k]); s += vv[k] * vv[k]; }
    } else {
        #pragma unroll
        for (int k = 0; k < 8; ++k) { hs[k] = 0; ls[k] = 0; }
    }
    uint4 H = make_uint4(hs[0] | (hs[1] << 16), hs[2] | (hs[3] << 16),
                         hs[4] | (hs[5] << 16), hs[6] | (hs[7] << 16));
    uint4 L = make_uint4(ls[0] | (ls[1] << 16), ls[2] | (ls[3] << 16),
                         ls[4] | (ls[5] << 16), ls[6] | (ls[7] << 16));
    *(uint4*)&ph[(size_t)p * NC + l * 8] = H;
    *(uint4*)&pl[(size_t)p * NC + l * 8] = L;
    for (int off = 32; off; off >>= 1) s += __shfl_down(s, off, 64);
    if (l == 0) p2[p] = s;
}

// ---------- main: split-bf16 MFMA GEMM + dists + fused min ----------
// m97 structure: 128x128 tile, BK=32, global_load_lds(16), linear LDS, 2 barriers/K-step.
__global__ __launch_bounds__(256) void gemm_kernel(
    const ushort_t* __restrict__ xh, const ushort_t* __restrict__ xl,
    const ushort_t* __restrict__ ph, const ushort_t* __restrict__ pl,
    const float* __restrict__ p2, const float* __restrict__ x2,
    float* __restrict__ dists, unsigned* __restrict__ mind)
{
    __shared__ ushort_t Ah[128 * 32];
    __shared__ ushort_t Al[128 * 32];
    __shared__ ushort_t Bh[128 * 32];
    __shared__ ushort_t Bl[128 * 32];

    // XCD-bijective swizzle: 1568 = 8*196; nt-slow -> 2 proto tiles per XCD chunk (L2-resident)
    const int wg  = blockIdx.x;
    const int swz = (wg & 7) * 196 + (wg >> 3);
    const int nt  = swz / 98, mt = swz - nt * 98;

    const int t = threadIdx.x;
    const int lane = t & 63, lm = lane & 15, kg = lane >> 4;
    const int w = t >> 6, wp = w >> 1, wx = w & 1;

    // staging: thread t covers (row = t>>2, col8 = (t&3)*8); issue q adds 64 rows.
    const size_t ga = (size_t)(mt * 128 + (t >> 2)) * NC + (t & 3) * 8;
    const size_t gb = (size_t)(nt * 128 + (t >> 2)) * NC + (t & 3) * 8;
    const size_t gs = (size_t)64 * NC;

    f32x4 acc[4][4];
    #pragma unroll
    for (int i = 0; i < 4; ++i)
        #pragma unroll
        for (int j = 0; j < 4; ++j) acc[i][j] = 0.f;

    for (int c0 = 0; c0 < NC; c0 += 32) {
        gl_lds16(xh + ga + c0,      &Ah[t * 8]);
        gl_lds16(xh + ga + gs + c0, &Ah[2048 + t * 8]);
        gl_lds16(xl + ga + c0,      &Al[t * 8]);
        gl_lds16(xl + ga + gs + c0, &Al[2048 + t * 8]);
        gl_lds16(ph + gb + c0,      &Bh[t * 8]);
        gl_lds16(ph + gb + gs + c0, &Bh[2048 + t * 8]);
        gl_lds16(pl + gb + c0,      &Bl[t * 8]);
        gl_lds16(pl + gb + gs + c0, &Bl[2048 + t * 8]);
        __syncthreads();   // compiler emits vmcnt(0) drain here

        short8 PH[4], PL[4], XH[4], XL[4];
        #pragma unroll
        for (int i = 0; i < 4; ++i) {
            PH[i] = *(const short8*)&Bh[(wp * 64 + i * 16 + lm) * 32 + kg * 8];
            PL[i] = *(const short8*)&Bl[(wp * 64 + i * 16 + lm) * 32 + kg * 8];
            XH[i] = *(const short8*)&Ah[(wx * 64 + i * 16 + lm) * 32 + kg * 8];
            XL[i] = *(const short8*)&Al[(wx * 64 + i * 16 + lm) * 32 + kg * 8];
        }
        #pragma unroll
        for (int i = 0; i < 4; ++i)
            #pragma unroll
            for (int j = 0; j < 4; ++j) {
                acc[i][j] = __builtin_amdgcn_mfma_f32_16x16x32_bf16(PH[i], XH[j], acc[i][j], 0, 0, 0);
                acc[i][j] = __builtin_amdgcn_mfma_f32_16x16x32_bf16(PL[i], XH[j], acc[i][j], 0, 0, 0);
                acc[i][j] = __builtin_amdgcn_mfma_f32_16x16x32_bf16(PH[i], XL[j], acc[i][j], 0, 0, 0);
            }
        __syncthreads();
    }

    // epilogue: dists = relu(x2 - 2*xp + p2); fused min over hw
    const int mhalf = mt * 128 + wx * 64;
    const int b0h = mhalf / 196;
    const int b1h = (mhalf + 63) / 196;     // may equal b0h
    float x2v[4]; int bj[4]; size_t dbase[4];
    #pragma unroll
    for (int j = 0; j < 4; ++j) {
        int m = mhalf + j * 16 + lm;
        x2v[j] = x2[m];
        int b = m / 196, hw = m - b * 196;
        bj[j] = b;
        dbase[j] = (size_t)b * ((size_t)NP * NHW) + hw;
    }
    #pragma unroll
    for (int i = 0; i < 4; ++i) {
        #pragma unroll
        for (int r = 0; r < 4; ++r) {
            int p = nt * 128 + wp * 64 + i * 16 + kg * 4 + r;   // uniform across lm group
            if (p < NP) {
                float p2v = p2[p];
                float mn0 = 3.402823466e38f, mn1 = 3.402823466e38f;
                #pragma unroll
                for (int j = 0; j < 4; ++j) {
                    float v = fmaxf(x2v[j] - 2.f * acc[i][j][r] + p2v, 0.f);
                    dists[dbase[j] + (size_t)p * NHW] = v;
                    if (bj[j] == b0h) mn0 = fminf(mn0, v); else mn1 = fminf(mn1, v);
                }
                #pragma unroll
                for (int off = 1; off < 16; off <<= 1) {
                    mn0 = fminf(mn0, __shfl_xor(mn0, off, 64));
                    mn1 = fminf(mn1, __shfl_xor(mn1, off, 64));
                }
                if (lm == 0) {
                    atomicMin(&mind[b0h * NP + p], __float_as_uint(mn0));
                    if (b1h != b0h) atomicMin(&mind[b1h * NP + p], __float_as_uint(mn1));
                }
            }
        }
    }
}

// ---------- activations from min_dists ----------
__global__ void act_kernel(const float* __restrict__ mind, float* __restrict__ act) {
    int i = blockIdx.x * 256 + threadIdx.x;
    if (i < NB * NP) { float md = mind[i]; act[i] = logf((md + 1.f) / (md + EPSV)); }
}

// ---------- logits = act @ fc^T ----------
__global__ void logits_kernel(const float* __restrict__ act,
                              const float* __restrict__ fc, float* __restrict__ out) {
    int r = blockIdx.x * 4 + (threadIdx.x >> 6);
    int l = threadIdx.x & 63;
    int b = r / NCL, n = r - b * NCL;
    const float* arow = act + b * NP;
    const float* frow = fc + n * NP;
    float s = 0.f;
    for (int k = l; k < NP; k += 64) s += arow[k] * frow[k];
    for (int off = 32; off; off >>= 1) s += __shfl_down(s, off, 64);
    if (l == 0) out[r] = s;
}

// ---------- x passthrough (LAST: overwrites xh/xl scratch) ----------
__global__ void copy_kernel(const float4* __restrict__ in, float4* __restrict__ out, int n4) {
    for (int i = blockIdx.x * blockDim.x + threadIdx.x; i < n4; i += gridDim.x * blockDim.x)
        out[i] = in[i];
}

extern "C" void kernel_launch(void* const* d_in, const int* in_sizes, int n_in,
                              void* d_out, int out_size, void* d_ws, size_t ws_size,
                              hipStream_t stream) {
    const float* x     = (const float*)d_in[0];
    const float* proto = (const float*)d_in[1];
    const float* fc    = (const float*)d_in[2];
    float* out = (float*)d_out;

    // x-region scratch (exact fit), overwritten by copy_kernel last
    ushort_t* xh = (ushort_t*)out;
    ushort_t* xl = xh + XTOT;
    // ws scratch: ph/pl (4MB) + p2 + x2  (~4.25MB total)
    ushort_t* ph = (ushort_t*)d_ws;
    ushort_t* pl = ph + (size_t)NPAD * NC;
    float*    p2 = (float*)(pl + (size_t)NPAD * NC);
    float*    x2 = p2 + NPAD;

    float* mind  = out + OFF_MIN;
    float* dists = out + OFF_D;
    float* act   = out + OFF_ACT;
    float* logit = out + OFF_LOG;

    fill_kernel<<<500, 256, 0, stream>>>(mind, x2);
    splitx_kernel<<<512, 256, 0, stream>>>(x, xh, xl, x2);
    splitp_kernel<<<512, 256, 0, stream>>>(proto, ph, pl, p2);

    gemm_kernel<<<1568, 256, 0, stream>>>(xh, xl, ph, pl, p2, x2, dists, (unsigned*)mind);

    act_kernel<<<500, 256, 0, stream>>>(mind, act);
    logits_kernel<<<3200, 256, 0, stream>>>(act, fc, logit);

    copy_kernel<<<2048, 256, 0, stream>>>((const float4*)x, (float4*)out, XTOT / 4);
}

// Round 8
// 262.582 us; speedup vs baseline: 1.2611x; 1.1622x over previous
//
#include <hip/hip_runtime.h>
#include <math.h>

// ProtoPNet forward on MI355X (gfx950).
// out concat: [x (6422528) | min_dists (128000) | dists (25088000) | activations (128000) | logits (12800)]

#define EPSV 1e-4f
typedef unsigned short ushort_t;

constexpr int NB  = 64;
constexpr int NC  = 512;
constexpr int NHW = 196;
constexpr int NP  = 2000;
constexpr int NPAD = 2048;
constexpr int NCL = 200;
constexpr int MM   = NB * NHW;        // 12544 = 98*128
constexpr int XTOT = NB * NC * NHW;   // 6422528

constexpr long long OFF_MIN = XTOT;
constexpr long long OFF_D   = OFF_MIN + (long long)NB * NP;
constexpr long long OFF_ACT = OFF_D + (long long)NB * NP * NHW;
constexpr long long OFF_LOG = OFF_ACT + (long long)NB * NP;

typedef __attribute__((ext_vector_type(8))) short short8;
typedef __attribute__((ext_vector_type(4))) float f32x4;

__device__ __forceinline__ unsigned bf16rne(float f) {
    unsigned u = __float_as_uint(f);
    return (u + 0x7FFFu + ((u >> 16) & 1u)) >> 16;
}

__device__ __forceinline__ void gl_lds16(const void* g, void* l) {
    __builtin_amdgcn_global_load_lds(
        (const __attribute__((address_space(1))) unsigned int*)g,
        (__attribute__((address_space(3))) unsigned int*)l, 16, 0, 0);
}

// ---------- proto -> ph [2048][512] bf16 (zero-pad, PRE-SWIZZLED per 64-chunk) + p2
//            ALSO: init mind=+MAX, x2=0 (runs FIRST) ----------
__global__ __launch_bounds__(256) void splitp_kernel(const float* __restrict__ proto,
                              ushort_t* __restrict__ ph, float* __restrict__ p2,
                              float* __restrict__ mind, float* __restrict__ x2) {
    int gi = blockIdx.x * 256 + threadIdx.x;      // < 131072
    if (gi < NB * NP) mind[gi] = 3.402823466e38f;
    if (gi < MM)      x2[gi]  = 0.f;

    int p = blockIdx.x * 4 + (threadIdx.x >> 6);  // < 2048
    int l = threadIdx.x & 63;                     // slot index (8 elems each)
    unsigned hs[8];
    float s = 0.f;
    if (p < NP) {
        const float4* pr = (const float4*)(proto + (size_t)p * NC + l * 8);
        float4 a = pr[0], bb = pr[1];
        float vv[8] = {a.x, a.y, a.z, a.w, bb.x, bb.y, bb.z, bb.w};
        #pragma unroll
        for (int k = 0; k < 8; ++k) { hs[k] = bf16rne(vv[k]); s += vv[k] * vv[k]; }
    } else {
        #pragma unroll
        for (int k = 0; k < 8; ++k) hs[k] = 0;
    }
    uint4 H = make_uint4(hs[0] | (hs[1] << 16), hs[2] | (hs[3] << 16),
                         hs[4] | (hs[5] << 16), hs[6] | (hs[7] << 16));
    // swizzle within 64-elem chunk: chunk = l>>3, slot-in-chunk = l&7 -> ^ (p&7)
    int col = (l >> 3) * 64 + (((l & 7) ^ (p & 7)) << 3);
    *(uint4*)&ph[(size_t)p * NC + col] = H;
    for (int off = 32; off; off >>= 1) s += __shfl_down(s, off, 64);
    if (l == 0) p2[p] = s;
}

// ---------- x -> xh [m][512] bf16 (transpose, PRE-SWIZZLED), x2 += partial ----------
__global__ __launch_bounds__(256) void splitx_kernel(const float* __restrict__ x,
                                                     ushort_t* __restrict__ xh,
                                                     float* __restrict__ x2) {
    __shared__ float tl[64 * 197];
    const int b = blockIdx.x >> 3, cc = blockIdx.x & 7;
    const int c0 = cc * 64;
    const float* src = x + ((size_t)b * NC + c0) * NHW;
    for (int idx = threadIdx.x; idx < 64 * 196; idx += 256)
        tl[(idx / 196) * 197 + (idx % 196)] = src[idx];
    __syncthreads();
    // phase 2: units = (hw, slot): 196*8 = 1568
    for (int idx = threadIdx.x; idx < 1568; idx += 256) {
        int hw = idx >> 3, slot = idx & 7;
        int m = b * 196 + hw;
        unsigned hs[8];
        #pragma unroll
        for (int e = 0; e < 8; ++e)
            hs[e] = bf16rne(tl[(slot * 8 + e) * 197 + hw]);
        uint4 H = make_uint4(hs[0] | (hs[1] << 16), hs[2] | (hs[3] << 16),
                             hs[4] | (hs[5] << 16), hs[6] | (hs[7] << 16));
        *(uint4*)&xh[(size_t)m * NC + c0 + ((slot ^ (m & 7)) << 3)] = H;
    }
    if (threadIdx.x < 196) {
        float s = 0.f;
        #pragma unroll 8
        for (int cl = 0; cl < 64; ++cl) { float v = tl[cl * 197 + threadIdx.x]; s += v * v; }
        atomicAdd(&x2[b * 196 + threadIdx.x], s);
    }
}

// ---------- main: bf16 MFMA GEMM + dists + fused min ----------
// 128x128 tile, BK=64, global_load_lds(16), XOR-swizzled LDS (T2 via pre-swizzled global).
__global__ __launch_bounds__(256) void gemm_kernel(
    const ushort_t* __restrict__ xh, const ushort_t* __restrict__ ph,
    const float* __restrict__ p2, const float* __restrict__ x2,
    float* __restrict__ dists, unsigned* __restrict__ mind)
{
    __shared__ ushort_t Ah[128 * 64];
    __shared__ ushort_t Bh[128 * 64];

    // XCD-bijective swizzle: 1568 = 8*196; nt-slow within XCD (B-tiles L2-resident)
    const int wg  = blockIdx.x;
    const int swz = (wg & 7) * 196 + (wg >> 3);
    const int nt  = swz / 98, mt = swz - nt * 98;

    const int t = threadIdx.x;
    const int lane = t & 63, lm = lane & 15, kg = lane >> 4;
    const int w = t >> 6, wp = w >> 1, wx = w & 1;

    // staging: thread t -> (row = t>>3, slot = t&7); each issue covers 32 rows
    const size_t ga = (size_t)(mt * 128 + (t >> 3)) * NC + (t & 7) * 8;
    const size_t gb = (size_t)(nt * 128 + (t >> 3)) * NC + (t & 7) * 8;
    const size_t gs = (size_t)32 * NC;

    f32x4 acc[4][4];
    #pragma unroll
    for (int i = 0; i < 4; ++i)
        #pragma unroll
        for (int j = 0; j < 4; ++j) acc[i][j] = 0.f;

    for (int c0 = 0; c0 < NC; c0 += 64) {
        #pragma unroll
        for (int q = 0; q < 4; ++q) {
            gl_lds16(xh + ga + q * gs + c0, &Ah[q * 2048 + t * 8]);
            gl_lds16(ph + gb + q * gs + c0, &Bh[q * 2048 + t * 8]);
        }
        __syncthreads();

        short8 PF[2][4], XF[2][4];
        #pragma unroll
        for (int s = 0; s < 2; ++s)
            #pragma unroll
            for (int i = 0; i < 4; ++i) {
                int prow = wp * 64 + i * 16 + lm;
                int xrow = wx * 64 + i * 16 + lm;
                int lsp = (s * 4 + kg) ^ (prow & 7);
                int lsx = (s * 4 + kg) ^ (xrow & 7);
                PF[s][i] = *(const short8*)&Bh[prow * 64 + lsp * 8];
                XF[s][i] = *(const short8*)&Ah[xrow * 64 + lsx * 8];
            }
        #pragma unroll
        for (int s = 0; s < 2; ++s)
            #pragma unroll
            for (int i = 0; i < 4; ++i)
                #pragma unroll
                for (int j = 0; j < 4; ++j)
                    acc[i][j] = __builtin_amdgcn_mfma_f32_16x16x32_bf16(PF[s][i], XF[s][j], acc[i][j], 0, 0, 0);
        __syncthreads();
    }

    // epilogue: dists = relu(x2 - 2*xp + p2) (nontemporal), fused min -> atomics
    const int mhalf = mt * 128 + wx * 64;
    const int b0h = mhalf / 196;
    const int b1h = (mhalf + 63) / 196;
    float x2v[4]; int bj[4]; size_t dbase[4];
    #pragma unroll
    for (int j = 0; j < 4; ++j) {
        int m = mhalf + j * 16 + lm;
        x2v[j] = x2[m];
        int b = m / 196, hw = m - b * 196;
        bj[j] = b;
        dbase[j] = (size_t)b * ((size_t)NP * NHW) + hw;
    }
    #pragma unroll
    for (int i = 0; i < 4; ++i) {
        #pragma unroll
        for (int r = 0; r < 4; ++r) {
            int p = nt * 128 + wp * 64 + i * 16 + kg * 4 + r;
            if (p < NP) {
                float p2v = p2[p];
                float mn0 = 3.402823466e38f, mn1 = 3.402823466e38f;
                #pragma unroll
                for (int j = 0; j < 4; ++j) {
                    float v = fmaxf(x2v[j] - 2.f * acc[i][j][r] + p2v, 0.f);
                    __builtin_nontemporal_store(v, &dists[dbase[j] + (size_t)p * NHW]);
                    if (bj[j] == b0h) mn0 = fminf(mn0, v); else mn1 = fminf(mn1, v);
                }
                #pragma unroll
                for (int off = 1; off < 16; off <<= 1) {
                    mn0 = fminf(mn0, __shfl_xor(mn0, off, 64));
                    mn1 = fminf(mn1, __shfl_xor(mn1, off, 64));
                }
                if (lm == 0) {
                    atomicMin(&mind[b0h * NP + p], __float_as_uint(mn0));
                    if (b1h != b0h) atomicMin(&mind[b1h * NP + p], __float_as_uint(mn1));
                }
            }
        }
    }
}

// ---------- activations ----------
__global__ void act_kernel(const float* __restrict__ mind, float* __restrict__ act) {
    int i = blockIdx.x * 256 + threadIdx.x;
    if (i < NB * NP) { float md = mind[i]; act[i] = logf((md + 1.f) / (md + EPSV)); }
}

// ---------- logits = act @ fc^T ----------
__global__ void logits_kernel(const float* __restrict__ act,
                              const float* __restrict__ fc, float* __restrict__ out) {
    int r = blockIdx.x * 4 + (threadIdx.x >> 6);
    int l = threadIdx.x & 63;
    int b = r / NCL, n = r - b * NCL;
    const float* arow = act + b * NP;
    const float* frow = fc + n * NP;
    float s = 0.f;
    for (int k = l; k < NP; k += 64) s += arow[k] * frow[k];
    for (int off = 32; off; off >>= 1) s += __shfl_down(s, off, 64);
    if (l == 0) out[r] = s;
}

// ---------- x passthrough (LAST: overwrites xh scratch) ----------
// ext_vector f32x4 (native clang vector) — __builtin_nontemporal_* rejects HIP_vector_type.
__global__ void copy_kernel(const f32x4* __restrict__ in, f32x4* __restrict__ out, int n4) {
    for (int i = blockIdx.x * blockDim.x + threadIdx.x; i < n4; i += gridDim.x * blockDim.x) {
        f32x4 v = __builtin_nontemporal_load(&in[i]);
        __builtin_nontemporal_store(v, &out[i]);
    }
}

extern "C" void kernel_launch(void* const* d_in, const int* in_sizes, int n_in,
                              void* d_out, int out_size, void* d_ws, size_t ws_size,
                              hipStream_t stream) {
    const float* x     = (const float*)d_in[0];
    const float* proto = (const float*)d_in[1];
    const float* fc    = (const float*)d_in[2];
    float* out = (float*)d_out;

    // x-region scratch: xh (12.8MB of 25.7MB), overwritten by copy_kernel last
    ushort_t* xh = (ushort_t*)out;
    // ws scratch: ph (2MB) + p2 + x2 (~2.06MB)
    ushort_t* ph = (ushort_t*)d_ws;
    float*    p2 = (float*)(ph + (size_t)NPAD * NC);
    float*    x2 = p2 + NPAD;

    float* mind  = out + OFF_MIN;
    float* dists = out + OFF_D;
    float* act   = out + OFF_ACT;
    float* logit = out + OFF_LOG;

    splitp_kernel<<<512, 256, 0, stream>>>(proto, ph, p2, mind, x2);  // also inits mind/x2
    splitx_kernel<<<512, 256, 0, stream>>>(x, xh, x2);

    gemm_kernel<<<1568, 256, 0, stream>>>(xh, ph, p2, x2, dists, (unsigned*)mind);

    act_kernel<<<500, 256, 0, stream>>>(mind, act);
    logits_kernel<<<3200, 256, 0, stream>>>(act, fc, logit);

    copy_kernel<<<2048, 256, 0, stream>>>((const f32x4*)x, (f32x4*)out, XTOT / 4);
}